// Round 5
// baseline (524.070 us; speedup 1.0000x reference)
//
#include <hip/hip_runtime.h>
#include <math.h>

#define BB 32
#define FF 512
#define TT 4000
#define HH 8
#define NCH 16     // t-chunks
#define CHT 256    // t per chunk (last chunk = 160 = 10 tiles)
#define TILE 16    // t per tile

// ---------------------------------------------------------------------------
// prep_qk: qk[h*512+f] = (1/8) * sum_d q[h,d] * Wk[h*64+d, f]
//          qb[h]       = (1/8) * sum_d q[h,d] * bk[h*64+d]
// ---------------------------------------------------------------------------
__global__ __launch_bounds__(256) void prep_qk(const float* __restrict__ q,
                                               const float* __restrict__ Wk,
                                               const float* __restrict__ bk,
                                               float* __restrict__ qk,
                                               float* __restrict__ qb) {
    int gid = blockIdx.x * 256 + threadIdx.x;   // 0..4095
    int h = gid >> 9, f = gid & 511;
    float s = 0.f;
#pragma unroll 8
    for (int d = 0; d < 64; ++d)
        s += q[h * 64 + d] * Wk[(size_t)(h * 64 + d) * FF + f];
    qk[gid] = s * 0.125f;
    if (gid < HH) {
        float sb = 0.f;
        for (int d = 0; d < 64; ++d) sb += q[gid * 64 + d] * bk[gid * 64 + d];
        qb[gid] = sb * 0.125f;
    }
}

// ---------------------------------------------------------------------------
// prep_wvt: WvT[f*512+hv] = Wv[hv*512+f] via 64x64 LDS tile.
// ---------------------------------------------------------------------------
__global__ __launch_bounds__(256) void prep_wvt(const float* __restrict__ Wv,
                                                float* __restrict__ WvT) {
    __shared__ float tile[64][65];
    int hv0 = blockIdx.x * 64, f0 = blockIdx.y * 64;
    int tj = threadIdx.x & 63, ti = threadIdx.x >> 6;
#pragma unroll
    for (int r = 0; r < 16; ++r) {
        int i = ti * 16 + r;
        tile[i][tj] = Wv[(size_t)(hv0 + i) * FF + f0 + tj];
    }
    __syncthreads();
#pragma unroll
    for (int r = 0; r < 16; ++r) {
        int i = ti * 16 + r;
        WvT[(size_t)(f0 + i) * FF + hv0 + tj] = tile[tj][i];
    }
}

// ---------------------------------------------------------------------------
// k_fused: single pass over x. Per block: (b, t-chunk). 512 threads = 8 waves.
// TILE=16, LDS ~71 KB -> 2 blocks/CU.
// ONCE-READ SCORE: wave w owns f-slice [64w,64w+64). Lane (tg=l&3,
// h=(l>>2)&7, sub=l>>5) serially FMAs the 32 rows of its half-slice into a
// private score[h][tg] float4 (f-reduction inside the accumulator, no
// shuffle tree). Per ds_read: 8 distinct 16B chunks (2 rows x 4 slots),
// 8-way head-broadcast, 2 rows/bank-group -> free 2-way. Tile is read from
// LDS exactly ONCE for score (was 8x). One __shfl_xor(32) merges sub-halves;
// per-wave slice-partials summed via 4KB pbuf (extra lgkm-only barrier).
// Softmax then per-head in wave w == head w, identical to before.
// Accumulate: thread f == tid, XOR t-slot staging, conflict-free (unchanged).
// ---------------------------------------------------------------------------
#define XS_WORDS (2 * FF * TILE)          // 16384 floats, 64 KB
#define PS_OFF   XS_WORDS                 // ps[8][16]
#define AL_OFF   (PS_OFF + HH * TILE)     // al8[8]
#define QB_OFF   (AL_OFF + 8)             // qb8[8]
#define PB_OFF   (QB_OFF + 8)             // pbuf[8][8][20]
#define PB_STRIDE 160                     // per source-wave: 8 heads * 20
#define LDS_FLOATS (PB_OFF + 8 * PB_STRIDE)   // 17808 floats = 71232 B

extern __shared__ float smem[];

__global__ __launch_bounds__(512, 4) void k_fused(
    const float* __restrict__ x, const int* __restrict__ wts,
    const float* __restrict__ qkg, const float* __restrict__ qbg,
    float* __restrict__ y_part, float* __restrict__ m_part,
    float* __restrict__ l_part) {
    float* xs   = smem;
    float* ps   = smem + PS_OFF;
    float* al8  = smem + AL_OFF;
    float* qb8  = smem + QB_OFF;
    float* pbuf = smem + PB_OFF;

    const int b = blockIdx.y, ch = blockIdx.x;
    const int tid = threadIdx.x;
    const int w = tid >> 6;          // wave index; softmax head == w
    const int l = tid & 63;
    const int tg  = l & 3;           // t-group 0..3
    const int hl  = (l >> 2) & 7;    // score-FMA head for this lane
    const int sub = l >> 5;          // half-slice 0/1
    const int tstart = ch * CHT;
    const int ntile = (ch == NCH - 1) ? 10 : 16;

    if (tid < 8) qb8[tid] = qbg[tid];

    // qk[hl][64w + 32sub + j] resident in registers (32 scalars)
    float qkr[32];
#pragma unroll
    for (int j = 0; j < 32; ++j)
        qkr[j] = qkg[hl * FF + (w << 6) + (sub << 5) + j];

    float yacc[8];
#pragma unroll
    for (int i = 0; i < 8; ++i) yacc[i] = 0.f;
    float m_run = -3.0e38f, l_run = 0.f;

    const float* xb = x + (size_t)b * FF * TT;
    const int* wb = wts + (size_t)b * TT;

    // DMA stage: 4 instrs of tile kt into buffer bi.
    // u = k*512 + tid -> row f = u>>2, slot = u&3; true t4g = slot ^ ((f>>1)&3).
    // LDS dest is wave-uniform base + lane*16.
#define STAGE(kt, bi, k0, k1)                                                  \
    {                                                                          \
        int t0_ = tstart + (kt) * TILE;                                        \
        _Pragma("unroll")                                                      \
        for (int k = (k0); k < (k1); ++k) {                                    \
            int u = k * 512 + tid;                                             \
            int f_ = u >> 2, sl = u & 3;                                       \
            int t4g = sl ^ ((f_ >> 1) & 3);                                    \
            const float* g = xb + (size_t)f_ * TT + t0_ + 4 * t4g;             \
            float* ldst = xs + (bi) * (FF * TILE) + (k * 512 + w * 64) * 4;    \
            __builtin_amdgcn_global_load_lds(                                  \
                (const __attribute__((address_space(1))) unsigned int*)g,      \
                (__attribute__((address_space(3))) unsigned int*)ldst,         \
                16, 0, 0);                                                     \
        }                                                                      \
    }

    STAGE(0, 0, 0, 4);
    __syncthreads();   // drains DMA; qb8 visible

    const float qbh = qb8[w];   // hoisted: never rewritten after init

    for (int kt = 0; kt < ntile; ++kt) {
        int cur = kt & 1, nxt = cur ^ 1;
        // next-tile stage up front: vmcnt coverage = whole tile
        if (kt + 1 < ntile) STAGE(kt + 1, nxt, 0, 4);

        // ---- score-partial phase: once-read, f-reduce in-register ----
        int tglob = tstart + kt * TILE + 4 * tg;
        int4 w4 = *(const int4*)(wb + tglob);          // mask, issued early
        const float* xcur = xs + cur * (FF * TILE);
        const float* xsl = xcur + ((w << 6) + (sub << 5)) * TILE;
        float4 sa = make_float4(0.f, 0.f, 0.f, 0.f);
        float4 sb = make_float4(0.f, 0.f, 0.f, 0.f);
#pragma unroll
        for (int j = 0; j < 32; j += 2) {
            int sw = 4 * (tg ^ ((j >> 1) & 3));        // same for j, j+1
            float4 x0 = *(const float4*)(xsl + 16 * j + sw);
            float4 x1 = *(const float4*)(xsl + 16 * (j + 1) + sw);
            float q0 = qkr[j], q1 = qkr[j + 1];
            sa.x += q0 * x0.x; sa.y += q0 * x0.y; sa.z += q0 * x0.z; sa.w += q0 * x0.w;
            sb.x += q1 * x1.x; sb.y += q1 * x1.y; sb.z += q1 * x1.z; sb.w += q1 * x1.w;
        }
        sa.x += sb.x; sa.y += sb.y; sa.z += sb.z; sa.w += sb.w;
        // merge sub-halves: butterfly xor-32 (both halves end with slice sum)
        sa.x += __shfl_xor(sa.x, 32);
        sa.y += __shfl_xor(sa.y, 32);
        sa.z += __shfl_xor(sa.z, 32);
        sa.w += __shfl_xor(sa.w, 32);
        if (l < 32)   // sub==0 lanes publish slice-partial for (hl, tg)
            *(float4*)(pbuf + w * PB_STRIDE + hl * 20 + 4 * tg) = sa;

        // barrier #1: publish pbuf (LDS only; DMA stays in flight)
        asm volatile("s_waitcnt lgkmcnt(0)" ::: "memory");
        __builtin_amdgcn_s_barrier();
        __builtin_amdgcn_sched_barrier(0);

        // ---- combine + softmax: wave w == head w (all lanes replicated) ----
        float4 s4 = make_float4(0.f, 0.f, 0.f, 0.f);
#pragma unroll
        for (int w2 = 0; w2 < 8; ++w2) {
            float4 p = *(const float4*)(pbuf + w2 * PB_STRIDE + w * 20 + 4 * tg);
            s4.x += p.x; s4.y += p.y; s4.z += p.z; s4.w += p.w;
        }
        float sm0 = w4.x ? (s4.x + qbh) : -1e30f;
        float sm1 = w4.y ? (s4.y + qbh) : -1e30f;
        float sm2 = w4.z ? (s4.z + qbh) : -1e30f;
        float sm3 = w4.w ? (s4.w + qbh) : -1e30f;
        float tm = fmaxf(fmaxf(sm0, sm1), fmaxf(sm2, sm3));
#pragma unroll
        for (int mk = 1; mk <= 2; mk <<= 1) tm = fmaxf(tm, __shfl_xor(tm, mk));
        float nm = fmaxf(m_run, tm);
        float al = __expf(m_run - nm);
        float e0 = w4.x ? __expf(sm0 - nm) : 0.f;
        float e1 = w4.y ? __expf(sm1 - nm) : 0.f;
        float e2 = w4.z ? __expf(sm2 - nm) : 0.f;
        float e3 = w4.w ? __expf(sm3 - nm) : 0.f;
        float ts = e0 + e1 + e2 + e3;
#pragma unroll
        for (int mk = 1; mk <= 2; mk <<= 1) ts += __shfl_xor(ts, mk);
        l_run = al * l_run + ts;
        m_run = nm;
        if (l < 4) *(float4*)(ps + w * TILE + 4 * tg) = make_float4(e0, e1, e2, e3);
        if (l == 0) al8[w] = al;

        // barrier #2: publish ps/al8 (LDS only; DMA stays in flight)
        asm volatile("s_waitcnt lgkmcnt(0)" ::: "memory");
        __builtin_amdgcn_s_barrier();
        __builtin_amdgcn_sched_barrier(0);

        // ---- accumulate phase: thread owns f = tid (conflict-free) ----
#pragma unroll
        for (int hh = 0; hh < 8; ++hh) yacc[hh] *= al8[hh];
        const float* xrow = xcur + tid * TILE;
        int fx = (tid >> 1) & 3;
#pragma unroll
        for (int g = 0; g < 4; ++g) {
            float4 xv = *(const float4*)(xrow + 4 * (g ^ fx));
#pragma unroll
            for (int hh = 0; hh < 8; ++hh) {
                float4 e4 = *(const float4*)(ps + hh * TILE + 4 * g);
                yacc[hh] += e4.x * xv.x + e4.y * xv.y + e4.z * xv.z + e4.w * xv.w;
            }
        }
        __syncthreads();   // full drain: nxt fully staged; cur/ps/pbuf reusable
    }

    // epilogue: per-chunk partials
#pragma unroll
    for (int hh = 0; hh < 8; ++hh)
        y_part[(((size_t)b * NCH + ch) * HH + hh) * FF + tid] = yacc[hh];
    if (l == 0) {
        m_part[(b * NCH + ch) * HH + w] = m_run;
        l_part[(b * NCH + ch) * HH + w] = l_run;
    }
}

// ---------------------------------------------------------------------------
// k_combine_out: merge chunk partials (flash-combine) then out = WvT . y + bv
// grid (2, 32); 256 threads.
// ---------------------------------------------------------------------------
__global__ __launch_bounds__(256) void k_combine_out(
    const float* __restrict__ y_part, const float* __restrict__ m_part,
    const float* __restrict__ l_part, const float* __restrict__ WvT,
    const float* __restrict__ bv, float* __restrict__ out) {
    __shared__ float ys[4][512];
    __shared__ float wj[4][NCH];
    __shared__ float invL[4], bsc[4];
    int half = blockIdx.x, b = blockIdx.y, tid = threadIdx.x;
    int h0 = half * 4;
    if (tid < 64) {
        int hl = tid >> 4, j = tid & 15;
        float m = m_part[(b * NCH + j) * HH + h0 + hl];
        float lv = l_part[(b * NCH + j) * HH + h0 + hl];
        float M = m;
#pragma unroll
        for (int mk = 1; mk <= 8; mk <<= 1) M = fmaxf(M, __shfl_xor(M, mk, 16));
        float a = __expf(m - M);
        float L = a * lv;
#pragma unroll
        for (int mk = 1; mk <= 8; mk <<= 1) L += __shfl_xor(L, mk, 16);
        wj[hl][j] = a;
        if (j == 0) {
            invL[hl] = (L > 0.f) ? 1.f / L : 0.f;
            bsc[hl] = (L > 0.f) ? 1.f : 0.f;
        }
    }
    __syncthreads();
    for (int i = tid; i < 2048; i += 256) {
        int hl = i >> 9, f = i & 511;
        float s = 0.f;
#pragma unroll
        for (int j = 0; j < NCH; ++j)
            s += wj[hl][j] * y_part[(((size_t)b * NCH + j) * HH + h0 + hl) * FF + f];
        ys[hl][f] = s * invL[hl];
    }
    __syncthreads();
    int hv = half * 256 + tid;
    int hloc = tid >> 6;
    const float* ysr = ys[hloc];
    float acc = 0.f;
#pragma unroll 8
    for (int f = 0; f < FF; ++f)
        acc += ysr[f] * WvT[(size_t)f * FF + hv];
    out[b * 512 + hv] = acc + bv[hv] * bsc[hloc];
}

// ---------------------------------------------------------------------------
// Workspace layout (floats):
//   qk 0 (4096) | qb 4096 (8) | WvT 8192 (262144)
//   y_part 270336 (32*16*8*512 = 2097152) | m_part 2367488 (4096)
//   l_part 2371584 (4096)
// ---------------------------------------------------------------------------
extern "C" void kernel_launch(void* const* d_in, const int* in_sizes, int n_in,
                              void* d_out, int out_size, void* d_ws, size_t ws_size,
                              hipStream_t stream) {
    const float* x   = (const float*)d_in[0];
    const int*   wts = (const int*)d_in[1];
    const float* q   = (const float*)d_in[2];
    const float* Wk  = (const float*)d_in[3];
    const float* bk  = (const float*)d_in[4];
    const float* Wv  = (const float*)d_in[5];
    const float* bv  = (const float*)d_in[6];
    float* out = (float*)d_out;
    float* ws  = (float*)d_ws;

    float* qk     = ws;
    float* qb     = ws + 4096;
    float* WvT    = ws + 8192;
    float* y_part = ws + 270336;
    float* m_part = ws + 2367488;
    float* l_part = ws + 2371584;

    prep_qk<<<16, 256, 0, stream>>>(q, Wk, bk, qk, qb);
    prep_wvt<<<dim3(8, 8), 256, 0, stream>>>(Wv, WvT);

    size_t lds_bytes = (size_t)LDS_FLOATS * 4;   // ~71 KB -> 2 blocks/CU
    (void)hipFuncSetAttribute((const void*)k_fused,
                              hipFuncAttributeMaxDynamicSharedMemorySize,
                              (int)lds_bytes);
    k_fused<<<dim3(NCH, BB), 512, lds_bytes, stream>>>(
        x, wts, qk, qb, y_part, m_part, l_part);

    k_combine_out<<<dim3(2, BB), 256, 0, stream>>>(
        y_part, m_part, l_part, WvT, bv, out);
}

// Round 6
// 469.457 us; speedup vs baseline: 1.1163x; 1.1163x over previous
//
#include <hip/hip_runtime.h>
#include <math.h>

#define BB 32
#define FF 512
#define TT 4000
#define HH 8
#define NCH 8      // t-chunks
#define CHT 512    // t per chunk (last chunk = 416 = 13 tiles)
#define TILE 32    // t per tile
#define PSTR 36    // ps row stride (32 used + 4 pad: de-conflicts split-acc e4 reads)

// ---------------------------------------------------------------------------
// prep_qk: qk[h*512+f] = (1/8) * sum_d q[h,d] * Wk[h*64+d, f]
//          qb[h]       = (1/8) * sum_d q[h,d] * bk[h*64+d]
// ---------------------------------------------------------------------------
__global__ __launch_bounds__(256) void prep_qk(const float* __restrict__ q,
                                               const float* __restrict__ Wk,
                                               const float* __restrict__ bk,
                                               float* __restrict__ qk,
                                               float* __restrict__ qb) {
    int gid = blockIdx.x * 256 + threadIdx.x;   // 0..4095
    int h = gid >> 9, f = gid & 511;
    float s = 0.f;
#pragma unroll 8
    for (int d = 0; d < 64; ++d)
        s += q[h * 64 + d] * Wk[(size_t)(h * 64 + d) * FF + f];
    qk[gid] = s * 0.125f;
    if (gid < HH) {
        float sb = 0.f;
        for (int d = 0; d < 64; ++d) sb += q[gid * 64 + d] * bk[gid * 64 + d];
        qb[gid] = sb * 0.125f;
    }
}

// ---------------------------------------------------------------------------
// prep_wvt: WvT[f*512+hv] = Wv[hv*512+f] via 64x64 LDS tile.
// ---------------------------------------------------------------------------
__global__ __launch_bounds__(256) void prep_wvt(const float* __restrict__ Wv,
                                                float* __restrict__ WvT) {
    __shared__ float tile[64][65];
    int hv0 = blockIdx.x * 64, f0 = blockIdx.y * 64;
    int tj = threadIdx.x & 63, ti = threadIdx.x >> 6;
#pragma unroll
    for (int r = 0; r < 16; ++r) {
        int i = ti * 16 + r;
        tile[i][tj] = Wv[(size_t)(hv0 + i) * FF + f0 + tj];
    }
    __syncthreads();
#pragma unroll
    for (int r = 0; r < 16; ++r) {
        int i = ti * 16 + r;
        WvT[(size_t)(f0 + i) * FF + hv0 + tj] = tile[tj][i];
    }
}

// ---------------------------------------------------------------------------
// k_fused: single pass over x. Per block: (b, t-chunk). 512 threads = 8 waves.
// Round-1 structure (TILE=32, 132 KB LDS, 1 blk/CU) with a SPLIT ACCUMULATE:
// thread owns 4 f-rows x 2 heads (48 LDS reads/tile vs 72) -- LDS issue
// cost is per-instruction, so reads scale as 4*f_cnt + 8*h_cnt, minimized
// by balancing f_cnt x h_cnt. Rows strided (fg+128r: slot swizzle invariant
// in r, 2-way bank-free); ps stride 36 de-conflicts the 4 per-hp e4 addrs.
// Score phase / softmax / staging / barriers identical to round 1.
// ---------------------------------------------------------------------------
#define XS_WORDS (2 * FF * TILE)          // 32768 floats, 128 KB
#define PS_OFF   XS_WORDS                 // ps[8][PSTR]
#define AL_OFF   (PS_OFF + HH * PSTR)     // al8[8]
#define QB_OFF   (AL_OFF + 8)             // qb8[8]
#define LDS_FLOATS (QB_OFF + 8)           // 33072 floats = 132288 B

extern __shared__ float smem[];

__global__ __launch_bounds__(512) void k_fused(
    const float* __restrict__ x, const int* __restrict__ wts,
    const float* __restrict__ qkg, const float* __restrict__ qbg,
    float* __restrict__ y_part, float* __restrict__ m_part,
    float* __restrict__ l_part) {
    float* xs  = smem;
    float* ps  = smem + PS_OFF;
    float* al8 = smem + AL_OFF;
    float* qb8 = smem + QB_OFF;

    const int b = blockIdx.y, ch = blockIdx.x;
    const int tid = threadIdx.x;
    const int w = tid >> 6;          // wave index == h
    const int l = tid & 63;
    const int t4 = l & 7;            // 0..7 : which 4-t group this lane scores
    const int fs = l >> 3;           // f-segment 0..7 (64 f each)
    const int f0 = fs * 64;
    const int h = w;
    const int hp = tid & 3;          // accumulate: head-pair index (heads 2hp,2hp+1)
    const int fg = tid >> 2;         // accumulate: base f-row (rows fg+128r)
    const int tstart = ch * CHT;
    const int ntile = (ch == NCH - 1) ? 13 : 16;

    if (tid < 8) qb8[tid] = qbg[tid];

    // qk[h][f0..f0+63] resident in registers (16 float4)
    float4 qkr[16];
#pragma unroll
    for (int j4 = 0; j4 < 16; ++j4)
        qkr[j4] = *(const float4*)(qkg + h * FF + f0 + 4 * j4);

    float yacc[4][2];
#pragma unroll
    for (int r = 0; r < 4; ++r) { yacc[r][0] = 0.f; yacc[r][1] = 0.f; }
    float m_run = -3.0e38f, l_run = 0.f;

    const float* xb = x + (size_t)b * FF * TT;
    const int* wb = wts + (size_t)b * TT;

    // DMA stage: instrs [k0,k1) of tile kt into buffer bi.
    // u = k*512 + tid -> f = u>>3, slot t4s = u&7; global t4 = t4s ^ (f&7).
    // LDS dest is wave-uniform base + lane*16.
#define STAGE(kt, bi, k0, k1)                                                  \
    {                                                                          \
        int t0_ = tstart + (kt) * TILE;                                        \
        _Pragma("unroll")                                                      \
        for (int k = (k0); k < (k1); ++k) {                                    \
            int u = k * 512 + tid;                                             \
            int f_ = u >> 3, t4s = u & 7;                                      \
            int t4g = t4s ^ (f_ & 7);                                          \
            const float* g = xb + (size_t)f_ * TT + t0_ + 4 * t4g;             \
            float* ldst = xs + (bi) * (FF * TILE) + (k * 512 + w * 64) * 4;    \
            __builtin_amdgcn_global_load_lds(                                  \
                (const __attribute__((address_space(1))) unsigned int*)g,      \
                (__attribute__((address_space(3))) unsigned int*)ldst,         \
                16, 0, 0);                                                     \
        }                                                                      \
    }

    STAGE(0, 0, 0, 8);
    __syncthreads();   // drains DMA; qb8 visible

    const float qbh = qb8[h];   // hoisted: never rewritten after init

    for (int kt = 0; kt < ntile; ++kt) {
        int cur = kt & 1, nxt = cur ^ 1;
        // first half of next tile's stage: streams during score phase
        if (kt + 1 < ntile) STAGE(kt + 1, nxt, 0, 4);

        // ---- score phase (reads cur) ----
        int tglob = tstart + kt * TILE + 4 * t4;
        int4 w4 = *(const int4*)(wb + tglob);          // mask, issued early
        const float* xcur = xs + cur * (FF * TILE);
        float4 s4 = make_float4(0.f, 0.f, 0.f, 0.f);
#pragma unroll
        for (int j4 = 0; j4 < 16; ++j4) {
            int f = f0 + 4 * j4;
            float4 qv = qkr[j4];
            float4 x0 = *(const float4*)(xcur + (f + 0) * TILE + 4 * (t4 ^ ((f + 0) & 7)));
            float4 x1 = *(const float4*)(xcur + (f + 1) * TILE + 4 * (t4 ^ ((f + 1) & 7)));
            float4 x2 = *(const float4*)(xcur + (f + 2) * TILE + 4 * (t4 ^ ((f + 2) & 7)));
            float4 x3 = *(const float4*)(xcur + (f + 3) * TILE + 4 * (t4 ^ ((f + 3) & 7)));
            s4.x += qv.x * x0.x + qv.y * x1.x + qv.z * x2.x + qv.w * x3.x;
            s4.y += qv.x * x0.y + qv.y * x1.y + qv.z * x2.y + qv.w * x3.y;
            s4.z += qv.x * x0.z + qv.y * x1.z + qv.z * x2.z + qv.w * x3.z;
            s4.w += qv.x * x0.w + qv.y * x1.w + qv.z * x2.w + qv.w * x3.w;
        }
        // reduce over f-segments (fs = l>>3 -> lanes xor 8,16,32)
#pragma unroll
        for (int mk = 8; mk <= 32; mk <<= 1) {
            s4.x += __shfl_xor(s4.x, mk);
            s4.y += __shfl_xor(s4.y, mk);
            s4.z += __shfl_xor(s4.z, mk);
            s4.w += __shfl_xor(s4.w, mk);
        }
        float sm0 = w4.x ? (s4.x + qbh) : -1e30f;
        float sm1 = w4.y ? (s4.y + qbh) : -1e30f;
        float sm2 = w4.z ? (s4.z + qbh) : -1e30f;
        float sm3 = w4.w ? (s4.w + qbh) : -1e30f;
        float tm = fmaxf(fmaxf(sm0, sm1), fmaxf(sm2, sm3));
#pragma unroll
        for (int mk = 1; mk <= 4; mk <<= 1) tm = fmaxf(tm, __shfl_xor(tm, mk));
        float nm = fmaxf(m_run, tm);
        float al = __expf(m_run - nm);
        float e0 = w4.x ? __expf(sm0 - nm) : 0.f;
        float e1 = w4.y ? __expf(sm1 - nm) : 0.f;
        float e2 = w4.z ? __expf(sm2 - nm) : 0.f;
        float e3 = w4.w ? __expf(sm3 - nm) : 0.f;
        float ts = e0 + e1 + e2 + e3;
#pragma unroll
        for (int mk = 1; mk <= 4; mk <<= 1) ts += __shfl_xor(ts, mk);
        l_run = al * l_run + ts;
        m_run = nm;
        if (fs == 0) *(float4*)(ps + h * PSTR + 4 * t4) = make_float4(e0, e1, e2, e3);
        if (l == 0) al8[h] = al;

        // publish ps/al8 (LDS only) WITHOUT draining the in-flight DMA:
        // raw s_barrier preceded by lgkmcnt(0). DMA targets xs[nxt]; the
        // accumulate phase reads only xs[cur]/ps, so vmcnt may stay hot.
        asm volatile("s_waitcnt lgkmcnt(0)" ::: "memory");
        __builtin_amdgcn_s_barrier();
        __builtin_amdgcn_sched_barrier(0);

        // second half of next tile's stage: streams during accumulate
        if (kt + 1 < ntile) STAGE(kt + 1, nxt, 4, 8);

        // ---- accumulate phase: thread owns rows fg+128r (r=0..3),
        //      heads 2hp, 2hp+1. 48 LDS reads vs 72 in the 1fx8h layout. ----
        float al0 = al8[2 * hp], al1 = al8[2 * hp + 1];
#pragma unroll
        for (int r = 0; r < 4; ++r) { yacc[r][0] *= al0; yacc[r][1] *= al1; }
        const float* xr0 = xcur + fg * TILE;
        const int fsw = fg & 7;          // slot swizzle base; 128r keeps row&7
#pragma unroll
        for (int g = 0; g < 8; ++g) {
            float4 ea = *(const float4*)(ps + (2 * hp) * PSTR + 4 * g);
            float4 eb = *(const float4*)(ps + (2 * hp + 1) * PSTR + 4 * g);
            int so = 4 * (g ^ fsw);
#pragma unroll
            for (int r = 0; r < 4; ++r) {
                float4 xv = *(const float4*)(xr0 + r * (128 * TILE) + so);
                yacc[r][0] += ea.x * xv.x + ea.y * xv.y + ea.z * xv.z + ea.w * xv.w;
                yacc[r][1] += eb.x * xv.x + eb.y * xv.y + eb.z * xv.z + eb.w * xv.w;
            }
        }
        __syncthreads();   // full drain: nxt fully staged; cur/ps free
    }

    // epilogue: per-chunk partials (split layout: 4 f-rows x 2 heads)
#pragma unroll
    for (int r = 0; r < 4; ++r)
#pragma unroll
        for (int c = 0; c < 2; ++c)
            y_part[(((size_t)b * NCH + ch) * HH + 2 * hp + c) * FF + fg + 128 * r] =
                yacc[r][c];
    if (l == 0) {
        m_part[(b * NCH + ch) * HH + h] = m_run;
        l_part[(b * NCH + ch) * HH + h] = l_run;
    }
}

// ---------------------------------------------------------------------------
// k_combine_out: merge chunk partials (flash-combine) then out = WvT . y + bv
// grid (2, 32); 256 threads.
// ---------------------------------------------------------------------------
__global__ __launch_bounds__(256) void k_combine_out(
    const float* __restrict__ y_part, const float* __restrict__ m_part,
    const float* __restrict__ l_part, const float* __restrict__ WvT,
    const float* __restrict__ bv, float* __restrict__ out) {
    __shared__ float ys[4][512];
    __shared__ float wj[4][NCH];
    __shared__ float invL[4], bsc[4];
    int half = blockIdx.x, b = blockIdx.y, tid = threadIdx.x;
    int h0 = half * 4;
    if (tid < 32) {
        int hl = tid >> 3, j = tid & 7;
        float m = m_part[(b * NCH + j) * HH + h0 + hl];
        float lv = l_part[(b * NCH + j) * HH + h0 + hl];
        float M = m;
#pragma unroll
        for (int mk = 1; mk <= 4; mk <<= 1) M = fmaxf(M, __shfl_xor(M, mk, 8));
        float a = __expf(m - M);
        float L = a * lv;
#pragma unroll
        for (int mk = 1; mk <= 4; mk <<= 1) L += __shfl_xor(L, mk, 8);
        wj[hl][j] = a;
        if (j == 0) {
            invL[hl] = (L > 0.f) ? 1.f / L : 0.f;
            bsc[hl] = (L > 0.f) ? 1.f : 0.f;
        }
    }
    __syncthreads();
    for (int i = tid; i < 2048; i += 256) {
        int hl = i >> 9, f = i & 511;
        float s = 0.f;
#pragma unroll
        for (int j = 0; j < NCH; ++j)
            s += wj[hl][j] * y_part[(((size_t)b * NCH + j) * HH + h0 + hl) * FF + f];
        ys[hl][f] = s * invL[hl];
    }
    __syncthreads();
    int hv = half * 256 + tid;
    int hloc = tid >> 6;
    const float* ysr = ys[hloc];
    float acc = 0.f;
#pragma unroll 8
    for (int f = 0; f < FF; ++f)
        acc += ysr[f] * WvT[(size_t)f * FF + hv];
    out[b * 512 + hv] = acc + bv[hv] * bsc[hloc];
}

// ---------------------------------------------------------------------------
// Workspace layout (floats):
//   qk 0 (4096) | qb 4096 (8) | WvT 8192 (262144)
//   y_part 270336 (32*8*8*512 = 1048576) | m_part 1318912 (2048)
//   l_part 1320960 (2048)
// ---------------------------------------------------------------------------
extern "C" void kernel_launch(void* const* d_in, const int* in_sizes, int n_in,
                              void* d_out, int out_size, void* d_ws, size_t ws_size,
                              hipStream_t stream) {
    const float* x   = (const float*)d_in[0];
    const int*   wts = (const int*)d_in[1];
    const float* q   = (const float*)d_in[2];
    const float* Wk  = (const float*)d_in[3];
    const float* bk  = (const float*)d_in[4];
    const float* Wv  = (const float*)d_in[5];
    const float* bv  = (const float*)d_in[6];
    float* out = (float*)d_out;
    float* ws  = (float*)d_ws;

    float* qk     = ws;
    float* qb     = ws + 4096;
    float* WvT    = ws + 8192;
    float* y_part = ws + 270336;
    float* m_part = ws + 1318912;
    float* l_part = ws + 1320960;

    prep_qk<<<16, 256, 0, stream>>>(q, Wk, bk, qk, qb);
    prep_wvt<<<dim3(8, 8), 256, 0, stream>>>(Wv, WvT);

    size_t lds_bytes = (size_t)LDS_FLOATS * 4;   // ~132 KB
    (void)hipFuncSetAttribute((const void*)k_fused,
                              hipFuncAttributeMaxDynamicSharedMemorySize,
                              (int)lds_bytes);
    k_fused<<<dim3(NCH, BB), 512, lds_bytes, stream>>>(
        x, wts, qk, qb, y_part, m_part, l_part);

    k_combine_out<<<dim3(2, BB), 256, 0, stream>>>(
        y_part, m_part, l_part, WvT, bv, out);
}